// Round 5
// baseline (395.215 us; speedup 1.0000x reference)
//
#include <hip/hip_runtime.h>

// B=2, S=2048, D=2048, H=16, DH=128. fp32 in/out, bf16 MFMA internally.
// prep (in-reg W transpose + x cast) -> fused QKV GEMM (256x128 tile, BK=64,
// 3-slot LDS ring, PER-PHASE m201 discipline: {ds_read + stage-issue ->
// barrier -> lgkmcnt(0) -> setprio MFMA x16 -> barrier}, counted vmcnt(6)
// at tile boundary only) -> flash attention (512-thr/8-wave, 256 q-rows,
// dbuf K/V LDS, FIXED-SHIFT softmax exp2(s-16), XCD-grouped) -> LN1 ->
// FF GEMM (same template) -> LN2.
// O kept in [B,H,S,DH]; reference's "buggy concat" is a flat view as [B,S,D].
// NOTES: (r4) per-wave acc <=64 f32. (r6) K-direct-to-VGPR regressed 2.5x.
// (r7) BK=64 + XOR swizzle = 0 bank conflicts. (r8) fixed-shift softmax
// safe: s~N(0,1.4^2). (r9) attn K-tile [kv][128] swizzle. (r10) LN
// vectorized. (r11) coarse 2-phase + counted vmcnt = only +7% (m248 "2ph"
// regime as the guide predicts; fine interleave is the lever, m196). (r12)
// attn 512-thr/256-qrow: staging per FLOP halved, attn ~90us/760TF. (r13)
// m201 per-phase barriers+lgkmcnt+setprio added to GEMM K-loop; syncs are
// strictly additive to the proven ring -> no new race surface. Failure
// criterion: qkv >=105us => m232-style null, revert.

#define B_ 2
#define S_ 2048
#define D_ 2048
#define H_ 16
#define DH_ 128

typedef __attribute__((ext_vector_type(8))) short s16x8;
typedef __attribute__((ext_vector_type(8))) unsigned short u16x8;
typedef __attribute__((ext_vector_type(4))) float f32x4;
typedef __attribute__((ext_vector_type(4))) unsigned short u16x4;

#define MFMA16(a, b, c) __builtin_amdgcn_mfma_f32_16x16x32_bf16(a, b, c, 0, 0, 0)

__device__ inline unsigned short f2bf(float f) {
  union { float f; unsigned u; } x; x.f = f;
  unsigned r = (x.u + 0x7fffu + ((x.u >> 16) & 1u)) >> 16;  // RNE
  return (unsigned short)r;
}
__device__ inline float bf2f(unsigned short u) {
  union { unsigned u; float f; } x; x.u = ((unsigned)u) << 16;
  return x.f;
}
__device__ inline unsigned pack2bf(float a, float b) {
  unsigned ua = __builtin_bit_cast(unsigned, a) + 0x8000u;
  unsigned ub = __builtin_bit_cast(unsigned, b) + 0x8000u;
  return __builtin_amdgcn_perm(ub, ua, 0x07060302u);  // {a.hi16, b.hi16}
}

__device__ inline void gld_lds16(const void* g, void* l) {
  __builtin_amdgcn_global_load_lds(
      (__attribute__((address_space(1))) void*)g,
      (__attribute__((address_space(3))) void*)l, 16, 0, 0);
}

// ------------------------------- prep: W transpose+cast x4 (z<4), x cast (z==4)
__global__ __launch_bounds__(256) void prep_kernel(
    const float* __restrict__ x, unsigned short* __restrict__ xb,
    const float* __restrict__ w0, const float* __restrict__ w1,
    const float* __restrict__ w2, const float* __restrict__ w3,
    unsigned short* __restrict__ o0, unsigned short* __restrict__ o1,
    unsigned short* __restrict__ o2, unsigned short* __restrict__ o3) {
  int z = blockIdx.z;
  int t = threadIdx.x;
  if (z == 4) {  // cast x
    int base = (blockIdx.y * 32 + blockIdx.x) * 16384 + t * 4;
#pragma unroll
    for (int p = 0; p < 16; ++p) {
      int i = base + p * 1024;
      float4 v = *(const float4*)&x[i];
      u16x4 o;
      o.x = f2bf(v.x); o.y = f2bf(v.y); o.z = f2bf(v.z); o.w = f2bf(v.w);
      *(u16x4*)&xb[i] = o;
    }
    return;
  }
  const float* W = z == 0 ? w0 : z == 1 ? w1 : z == 2 ? w2 : w3;
  unsigned short* WT = z == 0 ? o0 : z == 1 ? o1 : z == 2 ? o2 : o3;
  int n0 = blockIdx.x * 64, k0 = blockIdx.y * 128;
  int cl = t & 15, rw = t >> 4;
  int kb = k0 + rw * 8, nb = n0 + cl * 4;
  float4 f[8];
#pragma unroll
  for (int r = 0; r < 8; ++r) f[r] = *(const float4*)&W[(kb + r) * D_ + nb];
#define TPOSE(comp, i)                                                      \
  {                                                                         \
    u16x8 o = {f2bf(f[0].comp), f2bf(f[1].comp), f2bf(f[2].comp),           \
               f2bf(f[3].comp), f2bf(f[4].comp), f2bf(f[5].comp),           \
               f2bf(f[6].comp), f2bf(f[7].comp)};                           \
    *(u16x8*)&WT[(nb + i) * D_ + kb] = o;                                   \
  }
  TPOSE(x, 0) TPOSE(y, 1) TPOSE(z, 2) TPOSE(w, 3)
#undef TPOSE
}

// ---------------- GEMM, 256x128 tile, BK=64, 3-slot ring, m201 phase
// discipline. QKV=1: 3 weights (wi), Q scaled, V stored transposed.
// QKV=0: single weight, bf16 out to Qb.
template <int QKV>
__global__ __launch_bounds__(512, 1) void gemm8p_kernel(
    const unsigned short* __restrict__ A, const unsigned short* __restrict__ W0,
    const unsigned short* __restrict__ W1, const unsigned short* __restrict__ W2,
    const float* __restrict__ b0, const float* __restrict__ b1,
    const float* __restrict__ b2, unsigned short* __restrict__ Qb,
    unsigned short* __restrict__ Kb, unsigned short* __restrict__ Vt,
    float qscale) {
  __shared__ short As3[3][256 * 64];  // 96KB
  __shared__ short Bs3[3][128 * 64];  // 48KB
  int idx = blockIdx.x;
  const int nwg = QKV ? 768 : 256;
  const int cpx = nwg >> 3;
  int wg = (idx & 7) * cpx + (idx >> 3);  // XCD-bijective (nwg%8==0)
  int wi, mt, ntile;
  if (QKV) {
    wi = wg >> 8;
    int rem = wg & 255;
    mt = rem >> 4; ntile = rem & 15;
  } else {
    wi = 0; mt = wg >> 4; ntile = wg & 15;
  }
  int m0 = mt * 256, n0 = ntile * 128;
  const unsigned short* BT = QKV ? (wi == 0 ? W0 : wi == 1 ? W1 : W2) : W0;
  const float* bias = QKV ? (wi == 0 ? b0 : wi == 1 ? b1 : b2) : b0;
  float oscale = (QKV && wi == 0) ? qscale : 1.0f;

  int t = threadIdx.x, lane = t & 63, w = t >> 6;
  int nl = lane & 15, q = lane >> 4;
  int wr = (w >> 1) * 64, wc = (w & 1) * 64;  // 8 waves: 4M x 2N of 64x64
  int swz = nl & 7;

  // staging offsets: A 4 loads/thread/K-tile (256x64), B 2 (128x64).
  // LDS dst linear; SOURCE chunk pre-swizzled by row&7 (involution).
  int aoff[4], boff[2], aldst[4], bldst[2];
#pragma unroll
  for (int l = 0; l < 4; ++l) {
    int e = t + 512 * l;
    int row = e >> 3, c = e & 7;
    aoff[l] = (m0 + row) * 2048 + (c ^ (row & 7)) * 8;
    aldst[l] = e * 8;
  }
#pragma unroll
  for (int l = 0; l < 2; ++l) {
    int e = t + 512 * l;
    int row = e >> 3, c = e & 7;
    boff[l] = (n0 + row) * 2048 + (c ^ (row & 7)) * 8;
    bldst[l] = e * 8;
  }

  f32x4 acc[4][4];
  f32x4 z4 = {0.f, 0.f, 0.f, 0.f};
#pragma unroll
  for (int i = 0; i < 4; ++i)
#pragma unroll
    for (int j = 0; j < 4; ++j) acc[i][j] = z4;

  // prologue: stage K-tiles 0,1 into slots 0,1
#pragma unroll
  for (int kt = 0; kt < 2; ++kt) {
#pragma unroll
    for (int l = 0; l < 4; ++l)
      gld_lds16(&A[aoff[l] + kt * 64], &As3[kt][aldst[l]]);
#pragma unroll
    for (int l = 0; l < 2; ++l)
      gld_lds16(&BT[boff[l] + kt * 64], &Bs3[kt][bldst[l]]);
  }
  asm volatile("s_waitcnt vmcnt(6)" ::: "memory");  // tile 0 landed
  __builtin_amdgcn_s_barrier();

  int scur = 0;
  for (int kt = 0; kt < 32; ++kt) {
    const short* Asl = As3[scur];
    const short* Bsl = Bs3[scur];
    int sn = scur + 2; if (sn >= 3) sn -= 3;
    short* Ad = As3[sn];
    short* Bd = Bs3[sn];
    int kst = (kt + 2) * 64;
    bool st = kt < 30;  // tile kt+2 exists
    s16x8 af[4], bf[4];
    // ======== phase 0: kstep 0 (chunks q) ========
#pragma unroll
    for (int i = 0; i < 4; ++i)
      af[i] = *(const s16x8*)&Asl[(wr + i * 16 + nl) * 64 + (q ^ swz) * 8];
#pragma unroll
    for (int j = 0; j < 4; ++j)
      bf[j] = *(const s16x8*)&Bsl[(wc + j * 16 + nl) * 64 + (q ^ swz) * 8];
    if (st) {
      gld_lds16(&A[aoff[0] + kst], &Ad[aldst[0]]);
      gld_lds16(&A[aoff[1] + kst], &Ad[aldst[1]]);
      gld_lds16(&BT[boff[0] + kst], &Bd[bldst[0]]);
    }
    __builtin_amdgcn_s_barrier();
    asm volatile("s_waitcnt lgkmcnt(0)" ::: "memory");
    __builtin_amdgcn_sched_barrier(0);
    __builtin_amdgcn_s_setprio(1);
#pragma unroll
    for (int i = 0; i < 4; ++i)
#pragma unroll
      for (int j = 0; j < 4; ++j) acc[i][j] = MFMA16(af[i], bf[j], acc[i][j]);
    __builtin_amdgcn_s_setprio(0);
    __builtin_amdgcn_s_barrier();
    // ======== phase 1: kstep 1 (chunks 4+q) ========
#pragma unroll
    for (int i = 0; i < 4; ++i)
      af[i] = *(const s16x8*)&Asl[(wr + i * 16 + nl) * 64 + ((4 + q) ^ swz) * 8];
#pragma unroll
    for (int j = 0; j < 4; ++j)
      bf[j] = *(const s16x8*)&Bsl[(wc + j * 16 + nl) * 64 + ((4 + q) ^ swz) * 8];
    if (st) {
      gld_lds16(&A[aoff[2] + kst], &Ad[aldst[2]]);
      gld_lds16(&A[aoff[3] + kst], &Ad[aldst[3]]);
      gld_lds16(&BT[boff[1] + kst], &Bd[bldst[1]]);
    }
    __builtin_amdgcn_s_barrier();
    asm volatile("s_waitcnt lgkmcnt(0)" ::: "memory");
    __builtin_amdgcn_sched_barrier(0);
    __builtin_amdgcn_s_setprio(1);
#pragma unroll
    for (int i = 0; i < 4; ++i)
#pragma unroll
      for (int j = 0; j < 4; ++j) acc[i][j] = MFMA16(af[i], bf[j], acc[i][j]);
    __builtin_amdgcn_s_setprio(0);
    // ======== tile boundary: tile kt+1 landed; keep kt+2's 6 in flight ====
    if (kt < 31) {
      if (st)
        asm volatile("s_waitcnt vmcnt(6)" ::: "memory");
      else
        asm volatile("s_waitcnt vmcnt(0)" ::: "memory");
      __builtin_amdgcn_s_barrier();
    }
    scur = scur + 1; if (scur == 3) scur = 0;
  }

#pragma unroll
  for (int i = 0; i < 4; ++i)
#pragma unroll
    for (int j = 0; j < 4; ++j) {
      int row = m0 + wr + i * 16 + q * 4;
      int col = n0 + wc + j * 16 + nl;
      float bv = bias[col];
      float v[4];
#pragma unroll
      for (int r = 0; r < 4; ++r) v[r] = (acc[i][j][r] + bv) * oscale;
      if (QKV && wi == 2) {
        unsigned d0 = pack2bf(v[0], v[1]), d1 = pack2bf(v[2], v[3]);
        long idxv = ((long)(((row >> 11) * 16 + (col >> 7)) * 128 + (col & 127))) * 2048 +
                    (row & 2047);
        *(uint2*)&Vt[idxv] = (uint2){d0, d1};
      } else {
        unsigned short* out = (QKV && wi == 1) ? Kb : Qb;
#pragma unroll
        for (int r = 0; r < 4; ++r)
          out[(row + r) * 2048 + col] = f2bf(v[r]);
      }
    }
}

// ------------------------------------------- flash attention
// Block = (bh, 256 q rows), 8 waves x 32 qrows. KV tiles of 64 staged into
// double-buffered LDS serve 2x q-rows vs r9. FIXED-SHIFT softmax exp2(s-16).
// l per-lane, reduced once at end. XCD-grouped: 4 bh per XCD (4MB KV = L2).
// K tile [kv][128] chunk-XOR swizzled both-sides: 0 bank conflicts.
// LDS: 2x16K (K) + 2x16K (V) + 32K (Ps) = 96KB, 1 block/CU, 8 waves.
__global__ __launch_bounds__(512, 1) void attn_kernel(
    const unsigned short* __restrict__ Q, const unsigned short* __restrict__ K,
    const unsigned short* __restrict__ VT, unsigned short* __restrict__ O) {
  __shared__ short KsA[8192], KsB[8192];   // [kv][128] chunk-swizzled, 16KB each
  __shared__ short VsA[8192], VsB[8192];   // chunk-swizzled [d][kv], 16KB each
  __shared__ short Ps[16384];              // [qrow 0..255][kv], 16B-chunk XOR swizzle
  int t = threadIdx.x, lane = t & 63, w = t >> 6;
  int nl = lane & 15, q = lane >> 4;
  int i = blockIdx.x;
  int xcd = i & 7, j = i >> 3;
  int bh = xcd + 8 * (j & 3);
  int qb = j >> 2;
  int b = bh >> 4, h = bh & 15;

  // Q fragments (pre-scaled by 1/sqrt(DH)*log2e in the QKV GEMM)
  s16x8 qf[2][4];
  int qrow = b * S_ + qb * 256 + w * 32;
#pragma unroll
  for (int t2 = 0; t2 < 2; ++t2)
#pragma unroll
    for (int kc = 0; kc < 4; ++kc)
      qf[t2][kc] = *(const s16x8*)&Q[(qrow + t2 * 16 + nl) * D_ + h * DH_ + kc * 32 + q * 8];

  f32x4 z4 = {0.f, 0.f, 0.f, 0.f};
  f32x4 accO[2][8];
  f32x4 l4[2] = {z4, z4};
#pragma unroll
  for (int t2 = 0; t2 < 2; ++t2)
#pragma unroll
    for (int n8 = 0; n8 < 8; ++n8) accO[t2][n8] = z4;

  int swz = nl & 7;

  const unsigned short* kp[2];
  const unsigned short* vp[2];
#pragma unroll
  for (int i2 = 0; i2 < 2; ++i2) {
    int c = t + 512 * i2;
    int s = c >> 4, p = c & 15;
    kp[i2] = K + (long)(b * S_ + s) * D_ + h * DH_ + ((p ^ (s & 7)) * 8);
    int d = c >> 3, cp = c & 7, cs = cp ^ (d & 7);
    vp[i2] = VT + (long)(bh * DH_ + d) * S_ + cs * 8;
  }

#define STAGE(bufK, bufV)                           \
  {                                                 \
    _Pragma("unroll") for (int i2 = 0; i2 < 2; ++i2) { \
      gld_lds16(kp[i2], &bufK[(t + 512 * i2) * 8]); \
      gld_lds16(vp[i2], &bufV[(t + 512 * i2) * 8]); \
      kp[i2] += 64 * D_;                            \
      vp[i2] += 64;                                 \
    }                                               \
  }

  auto compute = [&](const short* Ks, const short* Vs) {
    f32x4 accS[2][4];
#pragma unroll
    for (int t2 = 0; t2 < 2; ++t2)
#pragma unroll
      for (int n = 0; n < 4; ++n) accS[t2][n] = z4;
    __builtin_amdgcn_s_setprio(1);
#pragma unroll
    for (int kc = 0; kc < 4; ++kc) {
      s16x8 kf[4];
#pragma unroll
      for (int n = 0; n < 4; ++n)
        kf[n] = *(const s16x8*)&Ks[(n * 16 + nl) * 128 +
                                   ((((kc << 2) + q) ^ swz)) * 8];
#pragma unroll
      for (int t2 = 0; t2 < 2; ++t2)
#pragma unroll
        for (int n = 0; n < 4; ++n)
          accS[t2][n] = MFMA16(kf[n], qf[t2][kc], accS[t2][n]);
    }
    __builtin_amdgcn_s_setprio(0);

#pragma unroll
    for (int t2 = 0; t2 < 2; ++t2) {
      int prow = (w * 32 + t2 * 16 + nl) * 64;
#pragma unroll
      for (int n = 0; n < 4; ++n) {
#pragma unroll
        for (int r = 0; r < 4; ++r)
          accS[t2][n][r] = __builtin_amdgcn_exp2f(accS[t2][n][r] - 16.0f);
        l4[t2] += accS[t2][n];
        unsigned d0 = pack2bf(accS[t2][n][0], accS[t2][n][1]);
        unsigned d1 = pack2bf(accS[t2][n][2], accS[t2][n][3]);
        int c8 = q + 4 * n;
        int off = prow + (((c8 >> 1) ^ swz) * 8 + (c8 & 1) * 4);
        *(uint2*)&Ps[off] = (uint2){d0, d1};
      }
    }

    __builtin_amdgcn_s_setprio(1);
#pragma unroll
    for (int ks = 0; ks < 2; ++ks) {
      s16x8 pf[2];
#pragma unroll
      for (int t2 = 0; t2 < 2; ++t2)
        pf[t2] = *(const s16x8*)&Ps[(w * 32 + t2 * 16 + nl) * 64 + ((4 * ks + q) ^ swz) * 8];
#pragma unroll
      for (int n8 = 0; n8 < 8; ++n8) {
        int d = n8 * 16 + nl;
        int cs = ks * 4 + q;
        int ci = d * 8 + (cs ^ (d & 7));
        s16x8 vf = *(const s16x8*)&Vs[ci * 8];
#pragma unroll
        for (int t2 = 0; t2 < 2; ++t2)
          accO[t2][n8] = MFMA16(vf, pf[t2], accO[t2][n8]);
      }
    }
    __builtin_amdgcn_s_setprio(0);
  };

  STAGE(KsA, VsA);  // tile 0
  for (int it = 0; it < 32; it += 2) {
    __syncthreads();
    STAGE(KsB, VsB);
    compute(KsA, VsA);
    __syncthreads();
    if (it + 2 < 32) STAGE(KsA, VsA);
    compute(KsB, VsB);
  }
#undef STAGE

#pragma unroll
  for (int t2 = 0; t2 < 2; ++t2) {
    float l = (l4[t2][0] + l4[t2][1]) + (l4[t2][2] + l4[t2][3]);
    l += __shfl_xor(l, 16);
    l += __shfl_xor(l, 32);
    float inv = 1.0f / l;
    int s = qb * 256 + w * 32 + t2 * 16 + nl;
    unsigned short* orow = &O[((long)(bh * S_ + s)) * DH_];
#pragma unroll
    for (int n8 = 0; n8 < 8; ++n8) {
      unsigned d0 = pack2bf(accO[t2][n8][0] * inv, accO[t2][n8][1] * inv);
      unsigned d1 = pack2bf(accO[t2][n8][2] * inv, accO[t2][n8][3] * inv);
      *(uint2*)&orow[n8 * 16 + q * 4] = (uint2){d0, d1};
    }
  }
}

// ------------------- LayerNorm: out = LN(A + O_flat)*gamma + beta
template <int OUTBF, int INBF>
__global__ __launch_bounds__(256) void ln_kernel(
    const void* __restrict__ Ain, const unsigned short* __restrict__ Ob,
    const float* __restrict__ gamma, const float* __restrict__ beta,
    void* __restrict__ out) {
  int row = blockIdx.x, t = threadIdx.x;
  int lane = t & 63, w = t >> 6;
  int c0 = t * 8;
  float v[8], s = 0.f, s2 = 0.f;
  u16x8 ob = *(const u16x8*)&Ob[row * D_ + c0];
  if (INBF) {
    u16x8 a = *(const u16x8*)&((const unsigned short*)Ain)[row * D_ + c0];
#pragma unroll
    for (int p = 0; p < 8; ++p) v[p] = bf2f(a[p]);
  } else {
    float4 a0 = *(const float4*)&((const float*)Ain)[row * D_ + c0];
    float4 a1 = *(const float4*)&((const float*)Ain)[row * D_ + c0 + 4];
    v[0] = a0.x; v[1] = a0.y; v[2] = a0.z; v[3] = a0.w;
    v[4] = a1.x; v[5] = a1.y; v[6] = a1.z; v[7] = a1.w;
  }
#pragma unroll
  for (int p = 0; p < 8; ++p) {
    v[p] += bf2f(ob[p]);
    s += v[p]; s2 += v[p] * v[p];
  }
#pragma unroll
  for (int mk = 32; mk >= 1; mk >>= 1) {
    s += __shfl_xor(s, mk);
    s2 += __shfl_xor(s2, mk);
  }
  __shared__ float red[8];
  if (lane == 0) { red[w * 2] = s; red[w * 2 + 1] = s2; }
  __syncthreads();
  s = red[0] + red[2] + red[4] + red[6];
  s2 = red[1] + red[3] + red[5] + red[7];
  float mu = s * (1.0f / D_);
  float var = s2 * (1.0f / D_) - mu * mu;
  float rs = rsqrtf(var + 1e-5f);
  float4 g0 = *(const float4*)&gamma[c0], g1 = *(const float4*)&gamma[c0 + 4];
  float4 b0 = *(const float4*)&beta[c0], b1 = *(const float4*)&beta[c0 + 4];
  float g[8] = {g0.x, g0.y, g0.z, g0.w, g1.x, g1.y, g1.z, g1.w};
  float bb[8] = {b0.x, b0.y, b0.z, b0.w, b1.x, b1.y, b1.z, b1.w};
  float o[8];
#pragma unroll
  for (int p = 0; p < 8; ++p) o[p] = (v[p] - mu) * rs * g[p] + bb[p];
  if (OUTBF) {
    u16x8 ov;
#pragma unroll
    for (int p = 0; p < 8; ++p) ov[p] = f2bf(o[p]);
    *(u16x8*)&((unsigned short*)out)[row * D_ + c0] = ov;
  } else {
    float4 o0 = {o[0], o[1], o[2], o[3]}, o1 = {o[4], o[5], o[6], o[7]};
    *(float4*)&((float*)out)[row * D_ + c0] = o0;
    *(float4*)&((float*)out)[row * D_ + c0 + 4] = o1;
  }
}

// ------------------------------------------- launch
extern "C" void kernel_launch(void* const* d_in, const int* in_sizes, int n_in,
                              void* d_out, int out_size, void* d_ws, size_t ws_size,
                              hipStream_t stream) {
  const float* x     = (const float*)d_in[0];
  const float* wq    = (const float*)d_in[1];
  const float* bq    = (const float*)d_in[2];
  const float* wk    = (const float*)d_in[3];
  const float* bk    = (const float*)d_in[4];
  const float* wv    = (const float*)d_in[5];
  const float* bv    = (const float*)d_in[6];
  const float* wf    = (const float*)d_in[7];
  const float* bfb   = (const float*)d_in[8];
  const float* gamma = (const float*)d_in[9];
  const float* beta  = (const float*)d_in[10];

  unsigned short* ws  = (unsigned short*)d_ws;
  unsigned short* WqT = ws;
  unsigned short* WkT = ws + 4194304;
  unsigned short* WvT = ws + 8388608;
  unsigned short* WfT = ws + 12582912;
  unsigned short* Xb  = ws + 16777216;
  unsigned short* Qb  = ws + 25165824;
  unsigned short* Kb  = ws + 33554432;
  unsigned short* Vt  = ws + 41943040;          // V^T written by QKV GEMM
  unsigned short* Ob  = Xb;                     // O over Xb (dead after QKV GEMM)
  unsigned short* H1  = Kb;                     // h1 over Kb (dead after attn)
  unsigned short* H2b = Vt;                     // h2 bf16 over Vt (dead after attn)

  const float scl2 = 0.08838834764831845f * 1.4426950408889634f;  // 1/sqrt(DH)*log2e

  dim3 blk(256);
  prep_kernel<<<dim3(32, 16, 5), blk, 0, stream>>>(
      x, Xb, wq, wk, wv, wf, WqT, WkT, WvT, WfT);

  gemm8p_kernel<1><<<dim3(768), dim3(512), 0, stream>>>(
      Xb, WqT, WkT, WvT, bq, bk, bv, Qb, Kb, Vt, scl2);

  attn_kernel<<<dim3(256), dim3(512), 0, stream>>>(Qb, Kb, Vt, Ob);

  ln_kernel<1, 0><<<dim3(4096), blk, 0, stream>>>(x, Ob, gamma, beta, (void*)H1);
  gemm8p_kernel<0><<<dim3(256), dim3(512), 0, stream>>>(
      H1, WfT, WfT, WfT, bfb, bfb, bfb, H2b, H2b, H2b, 1.0f);
  ln_kernel<0, 1><<<dim3(4096), blk, 0, stream>>>(H2b, Ob, gamma, beta, d_out);
}

// Round 6
// 380.753 us; speedup vs baseline: 1.0380x; 1.0380x over previous
//
#include <hip/hip_runtime.h>

// B=2, S=2048, D=2048, H=16, DH=128. fp32 in/out, bf16 MFMA internally.
// prep (W transpose via LDS staging -> coalesced writes; x cast) -> fused
// QKV GEMM (256x128 tile, BK=64, 3-slot LDS ring, counted vmcnt(6) + raw
// barriers, XOR-swizzled, V written transposed) -> flash attention
// (512-thr/8-wave, 256 q-rows, dbuf K/V LDS, FIXED-SHIFT softmax exp2(s-16),
// XCD-grouped) -> LN1 -> FF GEMM (same ring) -> LN2.
// O kept in [B,H,S,DH]; reference's "buggy concat" is a flat view as [B,S,D].
// NOTES: (r4) per-wave acc <=64 f32. (r6) K-direct-to-VGPR regressed 2.5x.
// (r7) BK=64 + XOR swizzle = 0 bank conflicts. (r8) fixed-shift softmax
// safe: s~N(0,1.4^2). (r9) attn K-tile [kv][128] swizzle. (r10) LN
// vectorized. (r11) coarse ring + counted vmcnt: qkv 118->110, +7% only.
// (r12) attn 512-thr/256-qrow: staging/FLOP halved. (r13) FAILED: m201
// per-phase barriers at this geometry regressed qkv to 118.6/MfmaUtil 36
// (graft without m201's exact balance adds lockstep cost; m232 quadrant).
// Reverted; GEMM plateau ~900TF is PARKED (2 structural attempts bracket it).
// (r14) prep W-transpose writes were 4x-uncoalesced (16B scattered at 16KB
// stride, 25% line util); now staged through padded LDS tile -> 256B
// coalesced stores. Reads and in-reg transpose unchanged.

#define B_ 2
#define S_ 2048
#define D_ 2048
#define H_ 16
#define DH_ 128

typedef __attribute__((ext_vector_type(8))) short s16x8;
typedef __attribute__((ext_vector_type(8))) unsigned short u16x8;
typedef __attribute__((ext_vector_type(4))) float f32x4;
typedef __attribute__((ext_vector_type(4))) unsigned short u16x4;

#define MFMA16(a, b, c) __builtin_amdgcn_mfma_f32_16x16x32_bf16(a, b, c, 0, 0, 0)

__device__ inline unsigned short f2bf(float f) {
  union { float f; unsigned u; } x; x.f = f;
  unsigned r = (x.u + 0x7fffu + ((x.u >> 16) & 1u)) >> 16;  // RNE
  return (unsigned short)r;
}
__device__ inline float bf2f(unsigned short u) {
  union { unsigned u; float f; } x; x.u = ((unsigned)u) << 16;
  return x.f;
}
__device__ inline unsigned pack2bf(float a, float b) {
  unsigned ua = __builtin_bit_cast(unsigned, a) + 0x8000u;
  unsigned ub = __builtin_bit_cast(unsigned, b) + 0x8000u;
  return __builtin_amdgcn_perm(ub, ua, 0x07060302u);  // {a.hi16, b.hi16}
}

__device__ inline void gld_lds16(const void* g, void* l) {
  __builtin_amdgcn_global_load_lds(
      (__attribute__((address_space(1))) void*)g,
      (__attribute__((address_space(3))) void*)l, 16, 0, 0);
}

// ------------------------------- prep: W transpose+cast x4 (z<4), x cast (z==4)
// r14: transpose staged through LDS. Reads: coalesced float4 rows of W.
// In-reg 8x4 transpose -> ds_write_b128 into [n][k] tile (stride 136 shorts,
// +8 pad). Barrier. Phase 2: contiguous LDS row reads -> fully coalesced
// 16B/lane global stores (consecutive lanes = consecutive 16B of one row).
__global__ __launch_bounds__(256) void prep_kernel(
    const float* __restrict__ x, unsigned short* __restrict__ xb,
    const float* __restrict__ w0, const float* __restrict__ w1,
    const float* __restrict__ w2, const float* __restrict__ w3,
    unsigned short* __restrict__ o0, unsigned short* __restrict__ o1,
    unsigned short* __restrict__ o2, unsigned short* __restrict__ o3) {
  int z = blockIdx.z;
  int t = threadIdx.x;
  if (z == 4) {  // cast x
    int base = (blockIdx.y * 32 + blockIdx.x) * 16384 + t * 4;
#pragma unroll
    for (int p = 0; p < 16; ++p) {
      int i = base + p * 1024;
      float4 v = *(const float4*)&x[i];
      u16x4 o;
      o.x = f2bf(v.x); o.y = f2bf(v.y); o.z = f2bf(v.z); o.w = f2bf(v.w);
      *(u16x4*)&xb[i] = o;
    }
    return;
  }
  __shared__ short Ts[64 * 136];  // [n 0..63][k 0..127], +8 short pad
  const float* W = z == 0 ? w0 : z == 1 ? w1 : z == 2 ? w2 : w3;
  unsigned short* WT = z == 0 ? o0 : z == 1 ? o1 : z == 2 ? o2 : o3;
  int n0 = blockIdx.x * 64, k0 = blockIdx.y * 128;
  int cl = t & 15, rw = t >> 4;
  int kb = k0 + rw * 8, nb = n0 + cl * 4;
  float4 f[8];
#pragma unroll
  for (int r = 0; r < 8; ++r) f[r] = *(const float4*)&W[(kb + r) * D_ + nb];
#define TPOSE(comp, i)                                                      \
  {                                                                         \
    u16x8 o = {f2bf(f[0].comp), f2bf(f[1].comp), f2bf(f[2].comp),           \
               f2bf(f[3].comp), f2bf(f[4].comp), f2bf(f[5].comp),           \
               f2bf(f[6].comp), f2bf(f[7].comp)};                           \
    *(u16x8*)&Ts[(cl * 4 + i) * 136 + rw * 8] = o;                          \
  }
  TPOSE(x, 0) TPOSE(y, 1) TPOSE(z, 2) TPOSE(w, 3)
#undef TPOSE
  __syncthreads();
#pragma unroll
  for (int p = 0; p < 4; ++p) {
    int e = t + 256 * p;
    int n = e >> 4, kc = e & 15;
    u16x8 o = *(const u16x8*)&Ts[n * 136 + kc * 8];
    *(u16x8*)&WT[(n0 + n) * D_ + k0 + kc * 8] = o;
  }
}

// ---------------- GEMM, 256x128 tile, BK=64, 3-slot ring, counted vmcnt.
// QKV=1: blockIdx covers 3 weights (wi), Q scaled, V stored transposed.
// QKV=0: single weight (W0/b0), bf16 out to Qb.
template <int QKV>
__global__ __launch_bounds__(512, 1) void gemm8p_kernel(
    const unsigned short* __restrict__ A, const unsigned short* __restrict__ W0,
    const unsigned short* __restrict__ W1, const unsigned short* __restrict__ W2,
    const float* __restrict__ b0, const float* __restrict__ b1,
    const float* __restrict__ b2, unsigned short* __restrict__ Qb,
    unsigned short* __restrict__ Kb, unsigned short* __restrict__ Vt,
    float qscale) {
  __shared__ short As3[3][256 * 64];  // 96KB
  __shared__ short Bs3[3][128 * 64];  // 48KB
  int idx = blockIdx.x;
  const int nwg = QKV ? 768 : 256;
  const int cpx = nwg >> 3;
  int wg = (idx & 7) * cpx + (idx >> 3);  // XCD-bijective (nwg%8==0)
  int wi, mt, ntile;
  if (QKV) {
    wi = wg >> 8;
    int rem = wg & 255;
    mt = rem >> 4; ntile = rem & 15;
  } else {
    wi = 0; mt = wg >> 4; ntile = wg & 15;
  }
  int m0 = mt * 256, n0 = ntile * 128;
  const unsigned short* BT = QKV ? (wi == 0 ? W0 : wi == 1 ? W1 : W2) : W0;
  const float* bias = QKV ? (wi == 0 ? b0 : wi == 1 ? b1 : b2) : b0;
  float oscale = (QKV && wi == 0) ? qscale : 1.0f;

  int t = threadIdx.x, lane = t & 63, w = t >> 6;
  int nl = lane & 15, q = lane >> 4;
  int wr = (w >> 1) * 64, wc = (w & 1) * 64;  // 8 waves: 4M x 2N of 64x64
  int swz = nl & 7;

  // staging offsets: A 4 loads/thread/K-tile (256x64), B 2 (128x64).
  // LDS dst linear; SOURCE chunk pre-swizzled by row&7 (involution).
  int aoff[4], boff[2], aldst[4], bldst[2];
#pragma unroll
  for (int l = 0; l < 4; ++l) {
    int e = t + 512 * l;
    int row = e >> 3, c = e & 7;
    aoff[l] = (m0 + row) * 2048 + (c ^ (row & 7)) * 8;
    aldst[l] = e * 8;
  }
#pragma unroll
  for (int l = 0; l < 2; ++l) {
    int e = t + 512 * l;
    int row = e >> 3, c = e & 7;
    boff[l] = (n0 + row) * 2048 + (c ^ (row & 7)) * 8;
    bldst[l] = e * 8;
  }

  f32x4 acc[4][4];
  f32x4 z4 = {0.f, 0.f, 0.f, 0.f};
#pragma unroll
  for (int i = 0; i < 4; ++i)
#pragma unroll
    for (int j = 0; j < 4; ++j) acc[i][j] = z4;

  // prologue: stage K-tiles 0,1 into slots 0,1
#pragma unroll
  for (int kt = 0; kt < 2; ++kt) {
#pragma unroll
    for (int l = 0; l < 4; ++l)
      gld_lds16(&A[aoff[l] + kt * 64], &As3[kt][aldst[l]]);
#pragma unroll
    for (int l = 0; l < 2; ++l)
      gld_lds16(&BT[boff[l] + kt * 64], &Bs3[kt][bldst[l]]);
  }
  asm volatile("s_waitcnt vmcnt(6)" ::: "memory");  // tile 0 landed
  __builtin_amdgcn_s_barrier();

  int scur = 0;
  for (int kt = 0; kt < 32; ++kt) {
    const short* Asl = As3[scur];
    const short* Bsl = Bs3[scur];
    int sn = scur + 2; if (sn >= 3) sn -= 3;
    short* Ad = As3[sn];
    short* Bd = Bs3[sn];
    int kst = (kt + 2) * 64;
    bool st = kt < 30;  // tile kt+2 exists
    s16x8 af[4], bf[4];
    // ---- phase 0: kstep 0 (chunks q)
#pragma unroll
    for (int i = 0; i < 4; ++i)
      af[i] = *(const s16x8*)&Asl[(wr + i * 16 + nl) * 64 + (q ^ swz) * 8];
#pragma unroll
    for (int j = 0; j < 4; ++j)
      bf[j] = *(const s16x8*)&Bsl[(wc + j * 16 + nl) * 64 + (q ^ swz) * 8];
    if (st) {
      gld_lds16(&A[aoff[0] + kst], &Ad[aldst[0]]);
      gld_lds16(&A[aoff[1] + kst], &Ad[aldst[1]]);
      gld_lds16(&BT[boff[0] + kst], &Bd[bldst[0]]);
    }
    __builtin_amdgcn_s_setprio(1);
#pragma unroll
    for (int i = 0; i < 4; ++i)
#pragma unroll
      for (int j = 0; j < 4; ++j) acc[i][j] = MFMA16(af[i], bf[j], acc[i][j]);
    __builtin_amdgcn_s_setprio(0);
    // ---- phase 1: kstep 1 (chunks 4+q)
#pragma unroll
    for (int i = 0; i < 4; ++i)
      af[i] = *(const s16x8*)&Asl[(wr + i * 16 + nl) * 64 + ((4 + q) ^ swz) * 8];
#pragma unroll
    for (int j = 0; j < 4; ++j)
      bf[j] = *(const s16x8*)&Bsl[(wc + j * 16 + nl) * 64 + ((4 + q) ^ swz) * 8];
    if (st) {
      gld_lds16(&A[aoff[2] + kst], &Ad[aldst[2]]);
      gld_lds16(&A[aoff[3] + kst], &Ad[aldst[3]]);
      gld_lds16(&BT[boff[1] + kst], &Bd[bldst[1]]);
    }
    __builtin_amdgcn_s_setprio(1);
#pragma unroll
    for (int i = 0; i < 4; ++i)
#pragma unroll
      for (int j = 0; j < 4; ++j) acc[i][j] = MFMA16(af[i], bf[j], acc[i][j]);
    __builtin_amdgcn_s_setprio(0);
    // ---- tile boundary: ensure tile kt+1 landed; keep kt+2's 6 in flight
    if (kt < 31) {
      if (st)
        asm volatile("s_waitcnt vmcnt(6)" ::: "memory");
      else
        asm volatile("s_waitcnt vmcnt(0)" ::: "memory");
      __builtin_amdgcn_s_barrier();
    }
    scur = scur + 1; if (scur == 3) scur = 0;
  }

#pragma unroll
  for (int i = 0; i < 4; ++i)
#pragma unroll
    for (int j = 0; j < 4; ++j) {
      int row = m0 + wr + i * 16 + q * 4;
      int col = n0 + wc + j * 16 + nl;
      float bv = bias[col];
      float v[4];
#pragma unroll
      for (int r = 0; r < 4; ++r) v[r] = (acc[i][j][r] + bv) * oscale;
      if (QKV && wi == 2) {
        unsigned d0 = pack2bf(v[0], v[1]), d1 = pack2bf(v[2], v[3]);
        long idxv = ((long)(((row >> 11) * 16 + (col >> 7)) * 128 + (col & 127))) * 2048 +
                    (row & 2047);
        *(uint2*)&Vt[idxv] = (uint2){d0, d1};
      } else {
        unsigned short* out = (QKV && wi == 1) ? Kb : Qb;
#pragma unroll
        for (int r = 0; r < 4; ++r)
          out[(row + r) * 2048 + col] = f2bf(v[r]);
      }
    }
}

// ------------------------------------------- flash attention
// Block = (bh, 256 q rows), 8 waves x 32 qrows. KV tiles of 64 staged into
// double-buffered LDS serve 2x q-rows vs r9. FIXED-SHIFT softmax exp2(s-16).
// l per-lane, reduced once at end. XCD-grouped: 4 bh per XCD (4MB KV = L2).
// K tile [kv][128] chunk-XOR swizzled both-sides: 0 bank conflicts.
// LDS: 2x16K (K) + 2x16K (V) + 32K (Ps) = 96KB, 1 block/CU, 8 waves.
__global__ __launch_bounds__(512, 1) void attn_kernel(
    const unsigned short* __restrict__ Q, const unsigned short* __restrict__ K,
    const unsigned short* __restrict__ VT, unsigned short* __restrict__ O) {
  __shared__ short KsA[8192], KsB[8192];   // [kv][128] chunk-swizzled, 16KB each
  __shared__ short VsA[8192], VsB[8192];   // chunk-swizzled [d][kv], 16KB each
  __shared__ short Ps[16384];              // [qrow 0..255][kv], 16B-chunk XOR swizzle
  int t = threadIdx.x, lane = t & 63, w = t >> 6;
  int nl = lane & 15, q = lane >> 4;
  int i = blockIdx.x;
  int xcd = i & 7, j = i >> 3;
  int bh = xcd + 8 * (j & 3);
  int qb = j >> 2;
  int b = bh >> 4, h = bh & 15;

  // Q fragments (pre-scaled by 1/sqrt(DH)*log2e in the QKV GEMM)
  s16x8 qf[2][4];
  int qrow = b * S_ + qb * 256 + w * 32;
#pragma unroll
  for (int t2 = 0; t2 < 2; ++t2)
#pragma unroll
    for (int kc = 0; kc < 4; ++kc)
      qf[t2][kc] = *(const s16x8*)&Q[(qrow + t2 * 16 + nl) * D_ + h * DH_ + kc * 32 + q * 8];

  f32x4 z4 = {0.f, 0.f, 0.f, 0.f};
  f32x4 accO[2][8];
  f32x4 l4[2] = {z4, z4};
#pragma unroll
  for (int t2 = 0; t2 < 2; ++t2)
#pragma unroll
    for (int n8 = 0; n8 < 8; ++n8) accO[t2][n8] = z4;

  int swz = nl & 7;

  const unsigned short* kp[2];
  const unsigned short* vp[2];
#pragma unroll
  for (int i2 = 0; i2 < 2; ++i2) {
    int c = t + 512 * i2;
    int s = c >> 4, p = c & 15;
    kp[i2] = K + (long)(b * S_ + s) * D_ + h * DH_ + ((p ^ (s & 7)) * 8);
    int d = c >> 3, cp = c & 7, cs = cp ^ (d & 7);
    vp[i2] = VT + (long)(bh * DH_ + d) * S_ + cs * 8;
  }

#define STAGE(bufK, bufV)                           \
  {                                                 \
    _Pragma("unroll") for (int i2 = 0; i2 < 2; ++i2) { \
      gld_lds16(kp[i2], &bufK[(t + 512 * i2) * 8]); \
      gld_lds16(vp[i2], &bufV[(t + 512 * i2) * 8]); \
      kp[i2] += 64 * D_;                            \
      vp[i2] += 64;                                 \
    }                                               \
  }

  auto compute = [&](const short* Ks, const short* Vs) {
    f32x4 accS[2][4];
#pragma unroll
    for (int t2 = 0; t2 < 2; ++t2)
#pragma unroll
      for (int n = 0; n < 4; ++n) accS[t2][n] = z4;
    __builtin_amdgcn_s_setprio(1);
#pragma unroll
    for (int kc = 0; kc < 4; ++kc) {
      s16x8 kf[4];
#pragma unroll
      for (int n = 0; n < 4; ++n)
        kf[n] = *(const s16x8*)&Ks[(n * 16 + nl) * 128 +
                                   ((((kc << 2) + q) ^ swz)) * 8];
#pragma unroll
      for (int t2 = 0; t2 < 2; ++t2)
#pragma unroll
        for (int n = 0; n < 4; ++n)
          accS[t2][n] = MFMA16(kf[n], qf[t2][kc], accS[t2][n]);
    }
    __builtin_amdgcn_s_setprio(0);

#pragma unroll
    for (int t2 = 0; t2 < 2; ++t2) {
      int prow = (w * 32 + t2 * 16 + nl) * 64;
#pragma unroll
      for (int n = 0; n < 4; ++n) {
#pragma unroll
        for (int r = 0; r < 4; ++r)
          accS[t2][n][r] = __builtin_amdgcn_exp2f(accS[t2][n][r] - 16.0f);
        l4[t2] += accS[t2][n];
        unsigned d0 = pack2bf(accS[t2][n][0], accS[t2][n][1]);
        unsigned d1 = pack2bf(accS[t2][n][2], accS[t2][n][3]);
        int c8 = q + 4 * n;
        int off = prow + (((c8 >> 1) ^ swz) * 8 + (c8 & 1) * 4);
        *(uint2*)&Ps[off] = (uint2){d0, d1};
      }
    }

    __builtin_amdgcn_s_setprio(1);
#pragma unroll
    for (int ks = 0; ks < 2; ++ks) {
      s16x8 pf[2];
#pragma unroll
      for (int t2 = 0; t2 < 2; ++t2)
        pf[t2] = *(const s16x8*)&Ps[(w * 32 + t2 * 16 + nl) * 64 + ((4 * ks + q) ^ swz) * 8];
#pragma unroll
      for (int n8 = 0; n8 < 8; ++n8) {
        int d = n8 * 16 + nl;
        int cs = ks * 4 + q;
        int ci = d * 8 + (cs ^ (d & 7));
        s16x8 vf = *(const s16x8*)&Vs[ci * 8];
#pragma unroll
        for (int t2 = 0; t2 < 2; ++t2)
          accO[t2][n8] = MFMA16(vf, pf[t2], accO[t2][n8]);
      }
    }
    __builtin_amdgcn_s_setprio(0);
  };

  STAGE(KsA, VsA);  // tile 0
  for (int it = 0; it < 32; it += 2) {
    __syncthreads();
    STAGE(KsB, VsB);
    compute(KsA, VsA);
    __syncthreads();
    if (it + 2 < 32) STAGE(KsA, VsA);
    compute(KsB, VsB);
  }
#undef STAGE

#pragma unroll
  for (int t2 = 0; t2 < 2; ++t2) {
    float l = (l4[t2][0] + l4[t2][1]) + (l4[t2][2] + l4[t2][3]);
    l += __shfl_xor(l, 16);
    l += __shfl_xor(l, 32);
    float inv = 1.0f / l;
    int s = qb * 256 + w * 32 + t2 * 16 + nl;
    unsigned short* orow = &O[((long)(bh * S_ + s)) * DH_];
#pragma unroll
    for (int n8 = 0; n8 < 8; ++n8) {
      unsigned d0 = pack2bf(accO[t2][n8][0] * inv, accO[t2][n8][1] * inv);
      unsigned d1 = pack2bf(accO[t2][n8][2] * inv, accO[t2][n8][3] * inv);
      *(uint2*)&orow[n8 * 16 + q * 4] = (uint2){d0, d1};
    }
  }
}

// ------------------- LayerNorm: out = LN(A + O_flat)*gamma + beta
template <int OUTBF, int INBF>
__global__ __launch_bounds__(256) void ln_kernel(
    const void* __restrict__ Ain, const unsigned short* __restrict__ Ob,
    const float* __restrict__ gamma, const float* __restrict__ beta,
    void* __restrict__ out) {
  int row = blockIdx.x, t = threadIdx.x;
  int lane = t & 63, w = t >> 6;
  int c0 = t * 8;
  float v[8], s = 0.f, s2 = 0.f;
  u16x8 ob = *(const u16x8*)&Ob[row * D_ + c0];
  if (INBF) {
    u16x8 a = *(const u16x8*)&((const unsigned short*)Ain)[row * D_ + c0];
#pragma unroll
    for (int p = 0; p < 8; ++p) v[p] = bf2f(a[p]);
  } else {
    float4 a0 = *(const float4*)&((const float*)Ain)[row * D_ + c0];
    float4 a1 = *(const float4*)&((const float*)Ain)[row * D_ + c0 + 4];
    v[0] = a0.x; v[1] = a0.y; v[2] = a0.z; v[3] = a0.w;
    v[4] = a1.x; v[5] = a1.y; v[6] = a1.z; v[7] = a1.w;
  }
#pragma unroll
  for (int p = 0; p < 8; ++p) {
    v[p] += bf2f(ob[p]);
    s += v[p]; s2 += v[p] * v[p];
  }
#pragma unroll
  for (int mk = 32; mk >= 1; mk >>= 1) {
    s += __shfl_xor(s, mk);
    s2 += __shfl_xor(s2, mk);
  }
  __shared__ float red[8];
  if (lane == 0) { red[w * 2] = s; red[w * 2 + 1] = s2; }
  __syncthreads();
  s = red[0] + red[2] + red[4] + red[6];
  s2 = red[1] + red[3] + red[5] + red[7];
  float mu = s * (1.0f / D_);
  float var = s2 * (1.0f / D_) - mu * mu;
  float rs = rsqrtf(var + 1e-5f);
  float4 g0 = *(const float4*)&gamma[c0], g1 = *(const float4*)&gamma[c0 + 4];
  float4 b0 = *(const float4*)&beta[c0], b1 = *(const float4*)&beta[c0 + 4];
  float g[8] = {g0.x, g0.y, g0.z, g0.w, g1.x, g1.y, g1.z, g1.w};
  float bb[8] = {b0.x, b0.y, b0.z, b0.w, b1.x, b1.y, b1.z, b1.w};
  float o[8];
#pragma unroll
  for (int p = 0; p < 8; ++p) o[p] = (v[p] - mu) * rs * g[p] + bb[p];
  if (OUTBF) {
    u16x8 ov;
#pragma unroll
    for (int p = 0; p < 8; ++p) ov[p] = f2bf(o[p]);
    *(u16x8*)&((unsigned short*)out)[row * D_ + c0] = ov;
  } else {
    float4 o0 = {o[0], o[1], o[2], o[3]}, o1 = {o[4], o[5], o[6], o[7]};
    *(float4*)&((float*)out)[row * D_ + c0] = o0;
    *(float4*)&((float*)out)[row * D_ + c0 + 4] = o1;
  }
}

// ------------------------------------------- launch
extern "C" void kernel_launch(void* const* d_in, const int* in_sizes, int n_in,
                              void* d_out, int out_size, void* d_ws, size_t ws_size,
                              hipStream_t stream) {
  const float* x     = (const float*)d_in[0];
  const float* wq    = (const float*)d_in[1];
  const float* bq    = (const float*)d_in[2];
  const float* wk    = (const float*)d_in[3];
  const float* bk    = (const float*)d_in[4];
  const float* wv    = (const float*)d_in[5];
  const float* bv    = (const float*)d_in[6];
  const float* wf    = (const float*)d_in[7];
  const float* bfb   = (const float*)d_in[8];
  const float* gamma = (const float*)d_in[9];
  const float* beta  = (const float*)d_in[10];

  unsigned short* ws  = (unsigned short*)d_ws;
  unsigned short* WqT = ws;
  unsigned short* WkT = ws + 4194304;
  unsigned short* WvT = ws + 8388608;
  unsigned short* WfT = ws + 12582912;
  unsigned short* Xb  = ws + 16777216;
  unsigned short* Qb  = ws + 25165824;
  unsigned short* Kb  = ws + 33554432;
  unsigned short* Vt  = ws + 41943040;          // V^T written by QKV GEMM
  unsigned short* Ob  = Xb;                     // O over Xb (dead after QKV GEMM)
  unsigned short* H1  = Kb;                     // h1 over Kb (dead after attn)
  unsigned short* H2b = Vt;                     // h2 bf16 over Vt (dead after attn)

  const float scl2 = 0.08838834764831845f * 1.4426950408889634f;  // 1/sqrt(DH)*log2e

  dim3 blk(256);
  prep_kernel<<<dim3(32, 16, 5), blk, 0, stream>>>(
      x, Xb, wq, wk, wv, wf, WqT, WkT, WvT, WfT);

  gemm8p_kernel<1><<<dim3(768), dim3(512), 0, stream>>>(
      Xb, WqT, WkT, WvT, bq, bk, bv, Qb, Kb, Vt, scl2);

  attn_kernel<<<dim3(256), dim3(512), 0, stream>>>(Qb, Kb, Vt, Ob);

  ln_kernel<1, 0><<<dim3(4096), blk, 0, stream>>>(x, Ob, gamma, beta, (void*)H1);
  gemm8p_kernel<0><<<dim3(256), dim3(512), 0, stream>>>(
      H1, WfT, WfT, WfT, bfb, bfb, bfb, H2b, H2b, H2b, 1.0f);
  ln_kernel<0, 1><<<dim3(4096), blk, 0, stream>>>(H2b, Ob, gamma, beta, d_out);
}